// Round 4
// baseline (331.200 us; speedup 1.0000x reference)
//
#include <hip/hip_runtime.h>
#include <hip/hip_bf16.h>

#define OUT1 16777216    // 4*64*256*256
#define BIG  33554432    // 4*128*256*256

typedef _Float16 half8 __attribute__((ext_vector_type(8)));
typedef float    floatx4 __attribute__((ext_vector_type(4)));

struct __align__(8) h4s { _Float16 x, y, z, w; };
__device__ inline void store4h(_Float16* p, float4 v){
    h4s t; t.x = (_Float16)v.x; t.y = (_Float16)v.y; t.z = (_Float16)v.z; t.w = (_Float16)v.w;
    *(h4s*)p = t;
}

// ---------------- K1: bilinear upsample 64x64 -> 256x256 (align_corners) + clip ----------------
__global__ __launch_bounds__(256) void k_prior(const float* __restrict__ prior, float* __restrict__ pu){
    int i = blockIdx.x*256 + threadIdx.x;       // 0..262143
    int b = i >> 16;
    int rem = i & 65535;
    int yy = rem >> 8, xx = rem & 255;
    const float scale = 63.0f/255.0f;
    float sy = yy*scale, sx = xx*scale;
    int y0 = min((int)floorf(sy), 63), x0 = min((int)floorf(sx), 63);
    int y1 = min(y0+1, 63), x1 = min(x0+1, 63);
    float wy = sy - (float)y0, wx = sx - (float)x0;
    const float* pb = prior + (b<<12);
    float v00 = pb[(y0<<6)+x0], v01 = pb[(y0<<6)+x1];
    float v10 = pb[(y1<<6)+x0], v11 = pb[(y1<<6)+x1];
    float r0 = v00*(1.f-wy) + v10*wy;
    float r1 = v01*(1.f-wy) + v11*wy;
    float v  = r0*(1.f-wx) + r1*wx;
    pu[i] = fminf(fmaxf(v, -1.f), 1.f);
}

// ---------------- K0: fold weights (f16): Wch(384x64), biases, -exp(A), Wof(64x128), bct ------
__global__ __launch_bounds__(256) void k_comb(const float* __restrict__ W_in, const float* __restrict__ b_in,
        const float* __restrict__ W_delta, const float* __restrict__ b_delta,
        const float* __restrict__ W_B, const float* __restrict__ b_B,
        const float* __restrict__ A_param, const float* __restrict__ W_out,
        _Float16* __restrict__ Wch, float* __restrict__ bcv, float* __restrict__ negA,
        _Float16* __restrict__ Wof, float* __restrict__ bct){
    int i = blockIdx.x*256 + threadIdx.x;
    if (i < 24576){
        int r = i >> 6, c = i & 63;
        float v;
        if (r < 128) v = W_in[i];
        else if (r < 256){
            int rr = r-128; float s = 0.f;
            for (int k=0;k<128;k++) s = fmaf(W_delta[(rr<<7)+k], W_in[(k<<6)+c], s);
            v = s;
        } else {
            int rr = r-256; float s = 0.f;
            for (int k=0;k<128;k++) s = fmaf(W_B[(rr<<7)+k], W_in[(k<<6)+c], s);
            v = s;
        }
        Wch[i] = (_Float16)v;
    } else if (i < 24960){
        int r = i - 24576; float v;
        if (r < 128) v = b_in[r];
        else if (r < 256){
            int rr=r-128; float s = b_delta[rr];
            for (int k=0;k<128;k++) s = fmaf(W_delta[(rr<<7)+k], b_in[k], s);
            v = s;
        } else {
            int rr=r-256; float s = b_B[rr];
            for (int k=0;k<128;k++) s = fmaf(W_B[(rr<<7)+k], b_in[k], s);
            v = s;
        }
        bcv[r] = v;
    } else if (i < 25088){
        negA[i-24960] = -expf(A_param[i-24960]);
    } else if (i < 33280){
        Wof[i-25088] = (_Float16)W_out[i-25088];   // [o][k] row-major, 64x128
    } else if (i < 33792){
        // interleaved per-channel epilogue table: bct[c] = (bI, bD, bB, -exp(A))  [float4]
        int j = i - 33280;                         // 0..511
        int c = j >> 2, comp = j & 3;
        float v;
        if (comp == 0) v = b_in[c];
        else if (comp == 1){
            float s = b_delta[c];
            for (int k=0;k<128;k++) s = fmaf(W_delta[(c<<7)+k], b_in[k], s);
            v = s;
        } else if (comp == 2){
            float s = b_B[c];
            for (int k=0;k<128;k++) s = fmaf(W_B[(c<<7)+k], b_in[k], s);
            v = s;
        } else {
            v = -expf(A_param[c]);
        }
        bct[j] = v;
    }
}

// ---------------- K2: MFMA projection v6 — persistent 4-chunk blocks, prefetch, bct float4 ----
// Grid 512 (2 blocks/CU), 512 threads, 48KB swizzled W LDS staged ONCE per block.
// Each block: 512-px span, 4 chunks x 128 px. Next chunk's 16 x-loads prefetched (f32 regs)
// before the current chunk's ct-loop -> sustained memory-level parallelism.
__global__ __launch_bounds__(512, 4) void k_proj_mfma(const float* __restrict__ x, const float* __restrict__ pu,
        const _Float16* __restrict__ Wch, const float* __restrict__ bct,
        const float* __restrict__ lam_p, const float* __restrict__ alp_p,
        _Float16* __restrict__ Ab, _Float16* __restrict__ Uu){
    __shared__ _Float16 Ws[24576];                 // 384 rows x 64 f16 = 48 KB, swizzled

    const int t    = threadIdx.x;                  // 0..511
    const int lane = t & 63;
    const int wave = t >> 6;                       // 0..7
    const int col  = lane & 15;
    const int quad = lane >> 4;

    const int bl      = blockIdx.x;                // 0..511
    const int b       = bl >> 7;
    const int px_base = (bl & 127) << 9;           // 512-px span per block

    // ---- stage Wch (384x64 f16 = 48 KB) into LDS, XOR-swizzled 16B granules ----
    {
        const float4* wsrc = (const float4*)Wch;   // 3072 x 16B chunks (8 per row)
        #pragma unroll
        for (int i = 0; i < 6; i++){
            int c = t + (i << 9);                  // 0..3071
            int row = c >> 3, part = c & 7;
            float4 v = wsrc[c];
            int byteoff = ((row << 7) + (part << 4)) ^ ((row & 7) << 4);
            *(float4*)((char*)Ws + byteoff) = v;
        }
    }

    const float lamv = lam_p[0], alpv = alp_p[0];
    const float* xcol = x + ((size_t)b<<22) + col; // + k*65536 + px

    // ---- prefetch chunk 0 A-values (f32) ----
    float xf0[8], xf1[8];
    {
        const float* xp = xcol + px_base + (wave<<4);
        #pragma unroll
        for (int j = 0; j < 8; j++){
            xf0[j] = xp[(size_t)(quad*8 + j) << 16];
            xf1[j] = xp[(size_t)(quad*8 + j + 32) << 16];
        }
    }

    __syncthreads();

    const int qb = quad << 4;                      // k-slot byte offset within row
    const char* wsb = (const char*)Ws;

    #pragma unroll 1
    for (int ch = 0; ch < 4; ch++){
        const int pxw = px_base + (ch << 7) + (wave << 4);

        // convert current chunk's A-fragments f32 -> f16
        half8 aX0, aX1;
        #pragma unroll
        for (int j = 0; j < 8; j++){
            aX0[j] = (_Float16)xf0[j];
            aX1[j] = (_Float16)xf1[j];
        }

        // prefetch next chunk (overlaps with this chunk's ct-loop)
        if (ch < 3){
            const float* xn = xcol + pxw + 128;
            #pragma unroll
            for (int j = 0; j < 8; j++){
                xf0[j] = xn[(size_t)(quad*8 + j) << 16];
                xf1[j] = xn[(size_t)(quad*8 + j + 32) << 16];
            }
        }

        // prior terms for this lane's 4 px
        float4 puv4 = *(const float4*)(pu + (b<<16) + pxw + (quad<<2));
        float lpu[4], apu[4];
        #pragma unroll
        for (int r = 0; r < 4; r++){
            float pv = ((const float*)&puv4)[r];
            lpu[r] = lamv * pv;
            apu[r] = fmaf(alpv, pv, 1.f);
        }

        #pragma unroll 2
        for (int ct = 0; ct < 8; ct++){
            int rI = (ct << 4) + col;              // I-group row
            int xr = (rI & 7) << 4;                // XOR term (same for I/D/B rows)
            half8 wI0 = *(const half8*)(wsb + ((( rI       << 7) +      qb) ^ xr));
            half8 wI1 = *(const half8*)(wsb + ((( rI       << 7) + 64 + qb) ^ xr));
            half8 wD0 = *(const half8*)(wsb + ((((rI + 128)<< 7) +      qb) ^ xr));
            half8 wD1 = *(const half8*)(wsb + ((((rI + 128)<< 7) + 64 + qb) ^ xr));
            half8 wB0 = *(const half8*)(wsb + ((((rI + 256)<< 7) +      qb) ^ xr));
            half8 wB1 = *(const half8*)(wsb + ((((rI + 256)<< 7) + 64 + qb) ^ xr));

            floatx4 aI = (floatx4){0.f,0.f,0.f,0.f};
            floatx4 aD = (floatx4){0.f,0.f,0.f,0.f};
            floatx4 aB = (floatx4){0.f,0.f,0.f,0.f};
            aI = __builtin_amdgcn_mfma_f32_16x16x32_f16(aX0, wI0, aI, 0, 0, 0);
            aD = __builtin_amdgcn_mfma_f32_16x16x32_f16(aX0, wD0, aD, 0, 0, 0);
            aB = __builtin_amdgcn_mfma_f32_16x16x32_f16(aX0, wB0, aB, 0, 0, 0);
            aI = __builtin_amdgcn_mfma_f32_16x16x32_f16(aX1, wI1, aI, 0, 0, 0);
            aD = __builtin_amdgcn_mfma_f32_16x16x32_f16(aX1, wD1, aD, 0, 0, 0);
            aB = __builtin_amdgcn_mfma_f32_16x16x32_f16(aX1, wB1, aB, 0, 0, 0);

            // epilogue: lane owns 4 consecutive px of channel ct*16+col
            int c = (ct<<4) + col;                 // channel 0..127
            float4 bv = *(const float4*)(bct + (c<<2));  // (bI, bD, bB, -expA)
            h4s oa, ou;
            #pragma unroll
            for (int r = 0; r < 4; r++){
                float sI = aI[r] + bv.x;
                float sD = aD[r] + bv.y;
                float sB = aB[r] + bv.z;
                float dpre  = sD + lpu[r];
                float delta = fmaxf(dpre, 0.f) + __logf(1.f + __expf(-fabsf(dpre)));
                float ab    = __expf(bv.w * delta);
                float uu    = delta * sB * apu[r] * sI;
                (&oa.x)[r] = (_Float16)ab;
                (&ou.x)[r] = (_Float16)uu;
            }
            size_t o = ((size_t)((b<<7) + c)<<16) + pxw + (quad<<2);
            *(h4s*)(Ab+o) = oa;
            *(h4s*)(Uu+o) = ou;
        }
    }
}

// ---------------- K3: scan along W — one wave per row, shuffle linear-recurrence scan ----------
__global__ __launch_bounds__(256) void k_scan_w(const _Float16* __restrict__ Ab, const _Float16* __restrict__ Uu,
                                                _Float16* __restrict__ Sw){
    int r    = (blockIdx.x<<2) + (threadIdx.x>>6);   // row id over (b,c,h): 0..131071
    int lane = threadIdx.x & 63;
    size_t base = ((size_t)r<<8) + (lane<<2);
    h4s a4 = *(const h4s*)(Ab+base);
    h4s u4 = *(const h4s*)(Uu+base);
    float ax=(float)a4.x, ay=(float)a4.y, az=(float)a4.z, aw=(float)a4.w;
    float ux=(float)u4.x, uy=(float)u4.y, uz=(float)u4.z, uw=(float)u4.w;
    float A = ax, U = ux;
    U = fmaf(ay, U, uy); A *= ay;
    U = fmaf(az, U, uz); A *= az;
    U = fmaf(aw, U, uw); A *= aw;
    #pragma unroll
    for (int off=1; off<64; off<<=1){
        float Apv = __shfl_up(A, off, 64);
        float Upv = __shfl_up(U, off, 64);
        if (lane >= off){ U = fmaf(A, Upv, U); A *= Apv; }
    }
    float h = __shfl_up(U, 1, 64);     // exclusive prefix
    if (lane == 0) h = 0.f;
    float4 o;
    h = fmaf(ax, h, ux); o.x = h;
    h = fmaf(ay, h, uy); o.y = h;
    h = fmaf(az, h, uz); o.z = h;
    h = fmaf(aw, h, uw); o.w = h;
    store4h(Sw+base, o);
}

// ---------------- K4: scan along H (thread per column) + add scanW -> Sh f16 ----------
__global__ __launch_bounds__(256) void k_scan_h(const _Float16* __restrict__ AbH, const _Float16* __restrict__ UuH,
                                                const _Float16* __restrict__ Sw, _Float16* __restrict__ Sh){
    int t   = blockIdx.x*256 + threadIdx.x;    // 0..131071
    int col = t >> 8;                          // b*128 + c
    int w   = t & 255;
    size_t base = ((size_t)col<<16) + w;
    float h = 0.f;
    #pragma unroll 4
    for (int hh=0; hh<256; hh++){
        size_t idx = base + ((size_t)hh<<8);
        float a = (float)AbH[idx];
        float u = (float)UuH[idx];
        float s = (float)Sw[idx];
        h = fmaf(a, h, u);
        Sh[idx] = (_Float16)(h + s);           // scanned = scanH + scanW
    }
}

// ---------------- K5: MFMA output conv (128->64) + residual — swapped operands v2 -------------
// A = Sh (m=pixel), B = Wof (n=out-ch). D: col=out-ch-in-tile, quad*4+r = px -> lane owns
// 4 consecutive px of one out-channel -> float4 stores + float4 x loads.
__global__ __launch_bounds__(256, 4) void k_out_mfma(const float* __restrict__ x, const _Float16* __restrict__ Sh,
        const _Float16* __restrict__ Wof, const float* __restrict__ bout, const float* __restrict__ gam_p,
        float* __restrict__ out){
    const int t    = threadIdx.x;
    const int lane = t & 63;
    const int wave = t >> 6;
    const int col  = lane & 15;
    const int quad = lane >> 4;
    const int b    = blockIdx.x >> 8;
    const int p0   = (blockIdx.x & 255) << 8;
    const int wn0  = wave << 6;                // this wave's 64 px

    const _Float16* shb = Sh + ((size_t)b<<23) + p0 + wn0;

    floatx4 acc[4][4];                         // [mt=px-tile][nt=out-ch-tile]
    #pragma unroll
    for (int mt = 0; mt < 4; mt++)
        #pragma unroll
        for (int nt = 0; nt < 4; nt++)
            acc[mt][nt] = (floatx4){0.f,0.f,0.f,0.f};

    #pragma unroll
    for (int kc = 0; kc < 4; kc++){
        half8 af[4];                           // Sh[m = wn0+mt*16+col][k = kc*32+quad*8+j]
        #pragma unroll
        for (int mt = 0; mt < 4; mt++)
            #pragma unroll
            for (int j = 0; j < 8; j++)
                af[mt][j] = shb[((size_t)(kc*32 + quad*8 + j)<<16) + mt*16 + col];
        half8 bf[4];                           // Wof[n = nt*16+col][k]  (16B vector loads)
        #pragma unroll
        for (int nt = 0; nt < 4; nt++)
            bf[nt] = *(const half8*)(Wof + (nt*16 + col)*128 + kc*32 + quad*8);
        #pragma unroll
        for (int mt = 0; mt < 4; mt++)
            #pragma unroll
            for (int nt = 0; nt < 4; nt++)
                acc[mt][nt] = __builtin_amdgcn_mfma_f32_16x16x32_f16(af[mt], bf[nt], acc[mt][nt], 0, 0, 0);
    }

    const float gv = gam_p[0];
    #pragma unroll
    for (int nt = 0; nt < 4; nt++){
        int o = nt*16 + col;                   // out channel 0..63
        float bo = bout[o];
        #pragma unroll
        for (int mt = 0; mt < 4; mt++){
            size_t idx = (((size_t)(b*64 + o))<<16) + p0 + wn0 + mt*16 + (quad<<2);
            float4 xv = *(const float4*)(x + idx);
            float4 ov;
            ov.x = fmaf(gv, acc[mt][nt][0] + bo, xv.x);
            ov.y = fmaf(gv, acc[mt][nt][1] + bo, xv.y);
            ov.z = fmaf(gv, acc[mt][nt][2] + bo, xv.z);
            ov.w = fmaf(gv, acc[mt][nt][3] + bo, xv.w);
            *(float4*)(out + idx) = ov;
        }
    }
}

extern "C" void kernel_launch(void* const* d_in, const int* in_sizes, int n_in,
                              void* d_out, int out_size, void* d_ws, size_t ws_size,
                              hipStream_t stream){
    const float* x       = (const float*)d_in[0];
    const float* prior   = (const float*)d_in[1];
    const float* W_in    = (const float*)d_in[2];
    const float* b_in    = (const float*)d_in[3];
    const float* W_out   = (const float*)d_in[4];
    const float* b_out   = (const float*)d_in[5];
    const float* W_delta = (const float*)d_in[6];
    const float* b_delta = (const float*)d_in[7];
    const float* W_B     = (const float*)d_in[8];
    const float* b_B     = (const float*)d_in[9];
    const float* A_param = (const float*)d_in[10];
    const float* lam     = (const float*)d_in[11];
    const float* alp     = (const float*)d_in[12];
    const float* gam     = (const float*)d_in[13];

    float* out = (float*)d_out;
    float* pu  = out + OUT1;                   // prior_up = output 1

    float* ws        = (float*)d_ws;
    _Float16* Wch    = (_Float16*)ws;          // 24576 f16 -> float-offset [0,12288)
    float* bcv       = ws + 12288;             // 384
    float* negA      = ws + 12672;             // 128
    _Float16* Wof    = (_Float16*)(ws + 12800);// 8192 f16 -> [12800,16896)
    float* bct       = ws + 16896;             // 512 floats (128 x float4)
    _Float16* AbH    = (_Float16*)(ws + 32768);// BIG f16
    _Float16* UuH    = AbH + BIG;              // BIG f16
    _Float16* Sh     = UuH + BIG;              // BIG f16   (total 201.5 MB)
    _Float16* Sw     = (_Float16*)out;         // f16 W-scan scratch in d_out[0:OUT1), 67 MB

    hipLaunchKernelGGL(k_prior,  dim3(1024),  dim3(256), 0, stream, prior, pu);
    hipLaunchKernelGGL(k_comb,   dim3(132),   dim3(256), 0, stream, W_in, b_in, W_delta, b_delta,
                       W_B, b_B, A_param, W_out, Wch, bcv, negA, Wof, bct);
    hipLaunchKernelGGL(k_proj_mfma, dim3(512), dim3(512), 0, stream,
                       x, pu, Wch, bct, lam, alp, AbH, UuH);
    hipLaunchKernelGGL(k_scan_w, dim3(32768), dim3(256), 0, stream, AbH, UuH, Sw);
    hipLaunchKernelGGL(k_scan_h, dim3(512),   dim3(256), 0, stream, AbH, UuH, Sw, Sh);
    hipLaunchKernelGGL(k_out_mfma, dim3(1024), dim3(256), 0, stream, x, Sh, Wof, b_out, gam, out);
}

// Round 5
// 284.092 us; speedup vs baseline: 1.1658x; 1.1658x over previous
//
#include <hip/hip_runtime.h>
#include <hip/hip_bf16.h>

#define OUT1 16777216    // 4*64*256*256
#define BIG  33554432    // 4*128*256*256

typedef _Float16 half8 __attribute__((ext_vector_type(8)));
typedef float    floatx4 __attribute__((ext_vector_type(4)));

struct __align__(8) h4s { _Float16 x, y, z, w; };

// ---------------- K1: bilinear upsample 64x64 -> 256x256 (align_corners) + clip ----------------
__global__ __launch_bounds__(256) void k_prior(const float* __restrict__ prior, float* __restrict__ pu){
    int i = blockIdx.x*256 + threadIdx.x;       // 0..262143
    int b = i >> 16;
    int rem = i & 65535;
    int yy = rem >> 8, xx = rem & 255;
    const float scale = 63.0f/255.0f;
    float sy = yy*scale, sx = xx*scale;
    int y0 = min((int)floorf(sy), 63), x0 = min((int)floorf(sx), 63);
    int y1 = min(y0+1, 63), x1 = min(x0+1, 63);
    float wy = sy - (float)y0, wx = sx - (float)x0;
    const float* pb = prior + (b<<12);
    float v00 = pb[(y0<<6)+x0], v01 = pb[(y0<<6)+x1];
    float v10 = pb[(y1<<6)+x0], v11 = pb[(y1<<6)+x1];
    float r0 = v00*(1.f-wy) + v10*wy;
    float r1 = v01*(1.f-wy) + v11*wy;
    float v  = r0*(1.f-wx) + r1*wx;
    pu[i] = fminf(fmaxf(v, -1.f), 1.f);
}

// ---------------- K0: fold weights (f16): Wch(384x64), biases, -exp(A), Wof(64x128), bct ------
__global__ __launch_bounds__(256) void k_comb(const float* __restrict__ W_in, const float* __restrict__ b_in,
        const float* __restrict__ W_delta, const float* __restrict__ b_delta,
        const float* __restrict__ W_B, const float* __restrict__ b_B,
        const float* __restrict__ A_param, const float* __restrict__ W_out,
        _Float16* __restrict__ Wch, float* __restrict__ bcv, float* __restrict__ negA,
        _Float16* __restrict__ Wof, float* __restrict__ bct){
    int i = blockIdx.x*256 + threadIdx.x;
    if (i < 24576){
        int r = i >> 6, c = i & 63;
        float v;
        if (r < 128) v = W_in[i];
        else if (r < 256){
            int rr = r-128; float s = 0.f;
            for (int k=0;k<128;k++) s = fmaf(W_delta[(rr<<7)+k], W_in[(k<<6)+c], s);
            v = s;
        } else {
            int rr = r-256; float s = 0.f;
            for (int k=0;k<128;k++) s = fmaf(W_B[(rr<<7)+k], W_in[(k<<6)+c], s);
            v = s;
        }
        Wch[i] = (_Float16)v;
    } else if (i < 24960){
        int r = i - 24576; float v;
        if (r < 128) v = b_in[r];
        else if (r < 256){
            int rr=r-128; float s = b_delta[rr];
            for (int k=0;k<128;k++) s = fmaf(W_delta[(rr<<7)+k], b_in[k], s);
            v = s;
        } else {
            int rr=r-256; float s = b_B[rr];
            for (int k=0;k<128;k++) s = fmaf(W_B[(rr<<7)+k], b_in[k], s);
            v = s;
        }
        bcv[r] = v;
    } else if (i < 25088){
        negA[i-24960] = -expf(A_param[i-24960]);
    } else if (i < 33280){
        Wof[i-25088] = (_Float16)W_out[i-25088];   // [o][k] row-major, 64x128
    } else if (i < 33792){
        // interleaved per-channel epilogue table: bct[c] = (bI, bD, bB, -exp(A))  [float4]
        int j = i - 33280;                         // 0..511
        int c = j >> 2, comp = j & 3;
        float v;
        if (comp == 0) v = b_in[c];
        else if (comp == 1){
            float s = b_delta[c];
            for (int k=0;k<128;k++) s = fmaf(W_delta[(c<<7)+k], b_in[k], s);
            v = s;
        } else if (comp == 2){
            float s = b_B[c];
            for (int k=0;k<128;k++) s = fmaf(W_B[(c<<7)+k], b_in[k], s);
            v = s;
        } else {
            v = -expf(A_param[c]);
        }
        bct[j] = v;
    }
}

// ---------------- K2: MFMA projection v6 — persistent 4-chunk blocks, prefetch, bct float4 ----
__global__ __launch_bounds__(512, 4) void k_proj_mfma(const float* __restrict__ x, const float* __restrict__ pu,
        const _Float16* __restrict__ Wch, const float* __restrict__ bct,
        const float* __restrict__ lam_p, const float* __restrict__ alp_p,
        _Float16* __restrict__ Ab, _Float16* __restrict__ Uu){
    __shared__ _Float16 Ws[24576];                 // 384 rows x 64 f16 = 48 KB, swizzled

    const int t    = threadIdx.x;                  // 0..511
    const int lane = t & 63;
    const int wave = t >> 6;                       // 0..7
    const int col  = lane & 15;
    const int quad = lane >> 4;

    const int bl      = blockIdx.x;                // 0..511
    const int b       = bl >> 7;
    const int px_base = (bl & 127) << 9;           // 512-px span per block

    // ---- stage Wch (384x64 f16 = 48 KB) into LDS, XOR-swizzled 16B granules ----
    {
        const float4* wsrc = (const float4*)Wch;   // 3072 x 16B chunks (8 per row)
        #pragma unroll
        for (int i = 0; i < 6; i++){
            int c = t + (i << 9);                  // 0..3071
            int row = c >> 3, part = c & 7;
            float4 v = wsrc[c];
            int byteoff = ((row << 7) + (part << 4)) ^ ((row & 7) << 4);
            *(float4*)((char*)Ws + byteoff) = v;
        }
    }

    const float lamv = lam_p[0], alpv = alp_p[0];
    const float* xcol = x + ((size_t)b<<22) + col; // + k*65536 + px

    // ---- prefetch chunk 0 A-values (f32) ----
    float xf0[8], xf1[8];
    {
        const float* xp = xcol + px_base + (wave<<4);
        #pragma unroll
        for (int j = 0; j < 8; j++){
            xf0[j] = xp[(size_t)(quad*8 + j) << 16];
            xf1[j] = xp[(size_t)(quad*8 + j + 32) << 16];
        }
    }

    __syncthreads();

    const int qb = quad << 4;                      // k-slot byte offset within row
    const char* wsb = (const char*)Ws;

    #pragma unroll 1
    for (int ch = 0; ch < 4; ch++){
        const int pxw = px_base + (ch << 7) + (wave << 4);

        // convert current chunk's A-fragments f32 -> f16
        half8 aX0, aX1;
        #pragma unroll
        for (int j = 0; j < 8; j++){
            aX0[j] = (_Float16)xf0[j];
            aX1[j] = (_Float16)xf1[j];
        }

        // prefetch next chunk (overlaps with this chunk's ct-loop)
        if (ch < 3){
            const float* xn = xcol + pxw + 128;
            #pragma unroll
            for (int j = 0; j < 8; j++){
                xf0[j] = xn[(size_t)(quad*8 + j) << 16];
                xf1[j] = xn[(size_t)(quad*8 + j + 32) << 16];
            }
        }

        // prior terms for this lane's 4 px
        float4 puv4 = *(const float4*)(pu + (b<<16) + pxw + (quad<<2));
        float lpu[4], apu[4];
        #pragma unroll
        for (int r = 0; r < 4; r++){
            float pv = ((const float*)&puv4)[r];
            lpu[r] = lamv * pv;
            apu[r] = fmaf(alpv, pv, 1.f);
        }

        #pragma unroll 2
        for (int ct = 0; ct < 8; ct++){
            int rI = (ct << 4) + col;              // I-group row
            int xr = (rI & 7) << 4;                // XOR term (same for I/D/B rows)
            half8 wI0 = *(const half8*)(wsb + ((( rI       << 7) +      qb) ^ xr));
            half8 wI1 = *(const half8*)(wsb + ((( rI       << 7) + 64 + qb) ^ xr));
            half8 wD0 = *(const half8*)(wsb + ((((rI + 128)<< 7) +      qb) ^ xr));
            half8 wD1 = *(const half8*)(wsb + ((((rI + 128)<< 7) + 64 + qb) ^ xr));
            half8 wB0 = *(const half8*)(wsb + ((((rI + 256)<< 7) +      qb) ^ xr));
            half8 wB1 = *(const half8*)(wsb + ((((rI + 256)<< 7) + 64 + qb) ^ xr));

            floatx4 aI = (floatx4){0.f,0.f,0.f,0.f};
            floatx4 aD = (floatx4){0.f,0.f,0.f,0.f};
            floatx4 aB = (floatx4){0.f,0.f,0.f,0.f};
            aI = __builtin_amdgcn_mfma_f32_16x16x32_f16(aX0, wI0, aI, 0, 0, 0);
            aD = __builtin_amdgcn_mfma_f32_16x16x32_f16(aX0, wD0, aD, 0, 0, 0);
            aB = __builtin_amdgcn_mfma_f32_16x16x32_f16(aX0, wB0, aB, 0, 0, 0);
            aI = __builtin_amdgcn_mfma_f32_16x16x32_f16(aX1, wI1, aI, 0, 0, 0);
            aD = __builtin_amdgcn_mfma_f32_16x16x32_f16(aX1, wD1, aD, 0, 0, 0);
            aB = __builtin_amdgcn_mfma_f32_16x16x32_f16(aX1, wB1, aB, 0, 0, 0);

            // epilogue: lane owns 4 consecutive px of channel ct*16+col
            int c = (ct<<4) + col;                 // channel 0..127
            float4 bv = *(const float4*)(bct + (c<<2));  // (bI, bD, bB, -expA)
            h4s oa, ou;
            #pragma unroll
            for (int r = 0; r < 4; r++){
                float sI = aI[r] + bv.x;
                float sD = aD[r] + bv.y;
                float sB = aB[r] + bv.z;
                float dpre  = sD + lpu[r];
                float delta = fmaxf(dpre, 0.f) + __logf(1.f + __expf(-fabsf(dpre)));
                float ab    = __expf(bv.w * delta);
                float uu    = delta * sB * apu[r] * sI;
                (&oa.x)[r] = (_Float16)ab;
                (&ou.x)[r] = (_Float16)uu;
            }
            size_t o = ((size_t)((b<<7) + c)<<16) + pxw + (quad<<2);
            *(h4s*)(Ab+o) = oa;
            *(h4s*)(Uu+o) = ou;
        }
    }
}

// ---------------- K34: fused W-scan + H-scan, one block per (b,c) plane ----------------------
// 512 threads = 8 waves. Group of 8 rows per iteration: wave v W-scans row 8g+v (K3's shuffle
// scan verbatim), parks (a, u, Wscan) f32 in LDS; then 256 column-threads apply the serial
// H-recurrence (K4's fma verbatim) and store Sh = Hcol + Wscan directly. Sw never materializes:
// 469 MB (K3+K4) -> 201 MB traffic.
__global__ __launch_bounds__(512) void k_scan_wh(const _Float16* __restrict__ Ab, const _Float16* __restrict__ Uu,
                                                 _Float16* __restrict__ Sh){
    __shared__ float As[8][256], Us[8][256], Wsc[8][256];   // 24 KB

    const int t    = threadIdx.x;
    const int lane = t & 63;
    const int wave = t >> 6;                       // 0..7 = row within group
    const size_t plane = (size_t)blockIdx.x << 16; // (b*128+c)*65536

    float Hcol = 0.f;                              // column state, thread t owns column t (t<256)

    // prefetch group 0: wave v reads row v (contiguous 512B per wave)
    size_t rb = plane + ((size_t)wave << 8) + (lane << 2);
    h4s a4 = *(const h4s*)(Ab + rb);
    h4s u4 = *(const h4s*)(Uu + rb);

    #pragma unroll 1
    for (int g = 0; g < 32; g++){
        float ax=(float)a4.x, ay=(float)a4.y, az=(float)a4.z, aw=(float)a4.w;
        float ux=(float)u4.x, uy=(float)u4.y, uz=(float)u4.z, uw=(float)u4.w;

        // prefetch next group while this one computes
        if (g < 31){
            size_t nb = plane + (((size_t)((g+1)<<3) + wave) << 8) + (lane << 2);
            a4 = *(const h4s*)(Ab + nb);
            u4 = *(const h4s*)(Uu + nb);
        }

        // ---- wave W-scan (identical to K3) ----
        float A = ax, U = ux;
        U = fmaf(ay, U, uy); A *= ay;
        U = fmaf(az, U, uz); A *= az;
        U = fmaf(aw, U, uw); A *= aw;
        #pragma unroll
        for (int off=1; off<64; off<<=1){
            float Apv = __shfl_up(A, off, 64);
            float Upv = __shfl_up(U, off, 64);
            if (lane >= off){ U = fmaf(A, Upv, U); A *= Apv; }
        }
        float h = __shfl_up(U, 1, 64);             // exclusive prefix
        if (lane == 0) h = 0.f;
        float4 o;
        h = fmaf(ax, h, ux); o.x = h;
        h = fmaf(ay, h, uy); o.y = h;
        h = fmaf(az, h, uz); o.z = h;
        h = fmaf(aw, h, uw); o.w = h;

        // ---- park row data in LDS ----
        int c0 = lane << 2;
        *(float4*)&As [wave][c0] = (float4){ax,ay,az,aw};
        *(float4*)&Us [wave][c0] = (float4){ux,uy,uz,uw};
        *(float4*)&Wsc[wave][c0] = o;
        __syncthreads();

        // ---- column phase: serial H-recurrence over the 8 rows (identical math to K4) ----
        if (t < 256){
            size_t sb = plane + ((size_t)(g<<3) << 8) + t;
            #pragma unroll
            for (int v = 0; v < 8; v++){
                Hcol = fmaf(As[v][t], Hcol, Us[v][t]);
                Sh[sb + ((size_t)v<<8)] = (_Float16)(Hcol + Wsc[v][t]);
            }
        }
        __syncthreads();
    }
}

// ---------------- K5: MFMA output conv (128->64) + residual — swapped operands v2 -------------
__global__ __launch_bounds__(256, 4) void k_out_mfma(const float* __restrict__ x, const _Float16* __restrict__ Sh,
        const _Float16* __restrict__ Wof, const float* __restrict__ bout, const float* __restrict__ gam_p,
        float* __restrict__ out){
    const int t    = threadIdx.x;
    const int lane = t & 63;
    const int wave = t >> 6;
    const int col  = lane & 15;
    const int quad = lane >> 4;
    const int b    = blockIdx.x >> 8;
    const int p0   = (blockIdx.x & 255) << 8;
    const int wn0  = wave << 6;                // this wave's 64 px

    const _Float16* shb = Sh + ((size_t)b<<23) + p0 + wn0;

    floatx4 acc[4][4];                         // [mt=px-tile][nt=out-ch-tile]
    #pragma unroll
    for (int mt = 0; mt < 4; mt++)
        #pragma unroll
        for (int nt = 0; nt < 4; nt++)
            acc[mt][nt] = (floatx4){0.f,0.f,0.f,0.f};

    #pragma unroll
    for (int kc = 0; kc < 4; kc++){
        half8 af[4];                           // Sh[m = wn0+mt*16+col][k = kc*32+quad*8+j]
        #pragma unroll
        for (int mt = 0; mt < 4; mt++)
            #pragma unroll
            for (int j = 0; j < 8; j++)
                af[mt][j] = shb[((size_t)(kc*32 + quad*8 + j)<<16) + mt*16 + col];
        half8 bf[4];                           // Wof[n = nt*16+col][k]  (16B vector loads)
        #pragma unroll
        for (int nt = 0; nt < 4; nt++)
            bf[nt] = *(const half8*)(Wof + (nt*16 + col)*128 + kc*32 + quad*8);
        #pragma unroll
        for (int mt = 0; mt < 4; mt++)
            #pragma unroll
            for (int nt = 0; nt < 4; nt++)
                acc[mt][nt] = __builtin_amdgcn_mfma_f32_16x16x32_f16(af[mt], bf[nt], acc[mt][nt], 0, 0, 0);
    }

    const float gv = gam_p[0];
    #pragma unroll
    for (int nt = 0; nt < 4; nt++){
        int o = nt*16 + col;                   // out channel 0..63
        float bo = bout[o];
        #pragma unroll
        for (int mt = 0; mt < 4; mt++){
            size_t idx = (((size_t)(b*64 + o))<<16) + p0 + wn0 + mt*16 + (quad<<2);
            float4 xv = *(const float4*)(x + idx);
            float4 ov;
            ov.x = fmaf(gv, acc[mt][nt][0] + bo, xv.x);
            ov.y = fmaf(gv, acc[mt][nt][1] + bo, xv.y);
            ov.z = fmaf(gv, acc[mt][nt][2] + bo, xv.z);
            ov.w = fmaf(gv, acc[mt][nt][3] + bo, xv.w);
            *(float4*)(out + idx) = ov;
        }
    }
}

extern "C" void kernel_launch(void* const* d_in, const int* in_sizes, int n_in,
                              void* d_out, int out_size, void* d_ws, size_t ws_size,
                              hipStream_t stream){
    const float* x       = (const float*)d_in[0];
    const float* prior   = (const float*)d_in[1];
    const float* W_in    = (const float*)d_in[2];
    const float* b_in    = (const float*)d_in[3];
    const float* W_out   = (const float*)d_in[4];
    const float* b_out   = (const float*)d_in[5];
    const float* W_delta = (const float*)d_in[6];
    const float* b_delta = (const float*)d_in[7];
    const float* W_B     = (const float*)d_in[8];
    const float* b_B     = (const float*)d_in[9];
    const float* A_param = (const float*)d_in[10];
    const float* lam     = (const float*)d_in[11];
    const float* alp     = (const float*)d_in[12];
    const float* gam     = (const float*)d_in[13];

    float* out = (float*)d_out;
    float* pu  = out + OUT1;                   // prior_up = output 1

    float* ws        = (float*)d_ws;
    _Float16* Wch    = (_Float16*)ws;          // 24576 f16 -> float-offset [0,12288)
    float* bcv       = ws + 12288;             // 384
    float* negA      = ws + 12672;             // 128
    _Float16* Wof    = (_Float16*)(ws + 12800);// 8192 f16 -> [12800,16896)
    float* bct       = ws + 16896;             // 512 floats (128 x float4)
    _Float16* AbH    = (_Float16*)(ws + 32768);// BIG f16
    _Float16* UuH    = AbH + BIG;              // BIG f16
    _Float16* Sh     = UuH + BIG;              // BIG f16   (total 201.5 MB)

    hipLaunchKernelGGL(k_prior,  dim3(1024),  dim3(256), 0, stream, prior, pu);
    hipLaunchKernelGGL(k_comb,   dim3(132),   dim3(256), 0, stream, W_in, b_in, W_delta, b_delta,
                       W_B, b_B, A_param, W_out, Wch, bcv, negA, Wof, bct);
    hipLaunchKernelGGL(k_proj_mfma, dim3(512), dim3(512), 0, stream,
                       x, pu, Wch, bct, lam, alp, AbH, UuH);
    hipLaunchKernelGGL(k_scan_wh, dim3(512), dim3(512), 0, stream, AbH, UuH, Sh);
    hipLaunchKernelGGL(k_out_mfma, dim3(1024), dim3(256), 0, stream, x, Sh, Wof, b_out, gam, out);
}

// Round 6
// 272.454 us; speedup vs baseline: 1.2156x; 1.0427x over previous
//
#include <hip/hip_runtime.h>
#include <hip/hip_bf16.h>

#define OUT1 16777216    // 4*64*256*256
#define BIG  33554432    // 4*128*256*256

typedef _Float16 half8 __attribute__((ext_vector_type(8)));
typedef float    floatx4 __attribute__((ext_vector_type(4)));

struct __align__(8) h4s { _Float16 x, y, z, w; };
struct __align__(16) au16 { h4s a, u; };         // 4 px of (a, u) interleaved, one 16-B unit

// ---------------- K1: bilinear upsample 64x64 -> 256x256 (align_corners) + clip ----------------
__global__ __launch_bounds__(256) void k_prior(const float* __restrict__ prior, float* __restrict__ pu){
    int i = blockIdx.x*256 + threadIdx.x;       // 0..262143
    int b = i >> 16;
    int rem = i & 65535;
    int yy = rem >> 8, xx = rem & 255;
    const float scale = 63.0f/255.0f;
    float sy = yy*scale, sx = xx*scale;
    int y0 = min((int)floorf(sy), 63), x0 = min((int)floorf(sx), 63);
    int y1 = min(y0+1, 63), x1 = min(x0+1, 63);
    float wy = sy - (float)y0, wx = sx - (float)x0;
    const float* pb = prior + (b<<12);
    float v00 = pb[(y0<<6)+x0], v01 = pb[(y0<<6)+x1];
    float v10 = pb[(y1<<6)+x0], v11 = pb[(y1<<6)+x1];
    float r0 = v00*(1.f-wy) + v10*wy;
    float r1 = v01*(1.f-wy) + v11*wy;
    float v  = r0*(1.f-wx) + r1*wx;
    pu[i] = fminf(fmaxf(v, -1.f), 1.f);
}

// ---------------- K0: fold weights (f16): Wch(384x64), biases, -exp(A), Wof(64x128), bct ------
__global__ __launch_bounds__(256) void k_comb(const float* __restrict__ W_in, const float* __restrict__ b_in,
        const float* __restrict__ W_delta, const float* __restrict__ b_delta,
        const float* __restrict__ W_B, const float* __restrict__ b_B,
        const float* __restrict__ A_param, const float* __restrict__ W_out,
        _Float16* __restrict__ Wch, float* __restrict__ bcv, float* __restrict__ negA,
        _Float16* __restrict__ Wof, float* __restrict__ bct){
    int i = blockIdx.x*256 + threadIdx.x;
    if (i < 24576){
        int r = i >> 6, c = i & 63;
        float v;
        if (r < 128) v = W_in[i];
        else if (r < 256){
            int rr = r-128; float s = 0.f;
            for (int k=0;k<128;k++) s = fmaf(W_delta[(rr<<7)+k], W_in[(k<<6)+c], s);
            v = s;
        } else {
            int rr = r-256; float s = 0.f;
            for (int k=0;k<128;k++) s = fmaf(W_B[(rr<<7)+k], W_in[(k<<6)+c], s);
            v = s;
        }
        Wch[i] = (_Float16)v;
    } else if (i < 24960){
        int r = i - 24576; float v;
        if (r < 128) v = b_in[r];
        else if (r < 256){
            int rr=r-128; float s = b_delta[rr];
            for (int k=0;k<128;k++) s = fmaf(W_delta[(rr<<7)+k], b_in[k], s);
            v = s;
        } else {
            int rr=r-256; float s = b_B[rr];
            for (int k=0;k<128;k++) s = fmaf(W_B[(rr<<7)+k], b_in[k], s);
            v = s;
        }
        bcv[r] = v;
    } else if (i < 25088){
        negA[i-24960] = -expf(A_param[i-24960]);
    } else if (i < 33280){
        Wof[i-25088] = (_Float16)W_out[i-25088];   // [o][k] row-major, 64x128
    } else if (i < 33792){
        // interleaved per-channel epilogue table: bct[c] = (bI, bD, bB, -exp(A))  [float4]
        int j = i - 33280;                         // 0..511
        int c = j >> 2, comp = j & 3;
        float v;
        if (comp == 0) v = b_in[c];
        else if (comp == 1){
            float s = b_delta[c];
            for (int k=0;k<128;k++) s = fmaf(W_delta[(c<<7)+k], b_in[k], s);
            v = s;
        } else if (comp == 2){
            float s = b_B[c];
            for (int k=0;k<128;k++) s = fmaf(W_B[(c<<7)+k], b_in[k], s);
            v = s;
        } else {
            v = -expf(A_param[c]);
        }
        bct[j] = v;
    }
}

// ---------------- K2: MFMA projection v7 — AU-interleaved 16-B stores ------------------------
// Grid 512 (2 blocks/CU), 512 threads, 48KB swizzled W LDS staged ONCE per block.
// Each block: 512-px span, 4 chunks x 128 px; next chunk's x-loads prefetched.
// Output: one au16 (4 px of a + u) per ct -> single dwordx4 store, 16 full 64-B segments/instr.
__global__ __launch_bounds__(512, 4) void k_proj_mfma(const float* __restrict__ x, const float* __restrict__ pu,
        const _Float16* __restrict__ Wch, const float* __restrict__ bct,
        const float* __restrict__ lam_p, const float* __restrict__ alp_p,
        au16* __restrict__ AU){
    __shared__ _Float16 Ws[24576];                 // 384 rows x 64 f16 = 48 KB, swizzled

    const int t    = threadIdx.x;                  // 0..511
    const int lane = t & 63;
    const int wave = t >> 6;                       // 0..7
    const int col  = lane & 15;
    const int quad = lane >> 4;

    const int bl      = blockIdx.x;                // 0..511
    const int b       = bl >> 7;
    const int px_base = (bl & 127) << 9;           // 512-px span per block

    // ---- stage Wch (384x64 f16 = 48 KB) into LDS, XOR-swizzled 16B granules ----
    {
        const float4* wsrc = (const float4*)Wch;   // 3072 x 16B chunks (8 per row)
        #pragma unroll
        for (int i = 0; i < 6; i++){
            int c = t + (i << 9);                  // 0..3071
            int row = c >> 3, part = c & 7;
            float4 v = wsrc[c];
            int byteoff = ((row << 7) + (part << 4)) ^ ((row & 7) << 4);
            *(float4*)((char*)Ws + byteoff) = v;
        }
    }

    const float lamv = lam_p[0], alpv = alp_p[0];
    const float* xcol = x + ((size_t)b<<22) + col; // + k*65536 + px

    // ---- prefetch chunk 0 A-values (f32) ----
    float xf0[8], xf1[8];
    {
        const float* xp = xcol + px_base + (wave<<4);
        #pragma unroll
        for (int j = 0; j < 8; j++){
            xf0[j] = xp[(size_t)(quad*8 + j) << 16];
            xf1[j] = xp[(size_t)(quad*8 + j + 32) << 16];
        }
    }

    __syncthreads();

    const int qb = quad << 4;                      // k-slot byte offset within row
    const char* wsb = (const char*)Ws;

    #pragma unroll 1
    for (int ch = 0; ch < 4; ch++){
        const int pxw = px_base + (ch << 7) + (wave << 4);

        // convert current chunk's A-fragments f32 -> f16
        half8 aX0, aX1;
        #pragma unroll
        for (int j = 0; j < 8; j++){
            aX0[j] = (_Float16)xf0[j];
            aX1[j] = (_Float16)xf1[j];
        }

        // prefetch next chunk (overlaps with this chunk's ct-loop)
        if (ch < 3){
            const float* xn = xcol + pxw + 128;
            #pragma unroll
            for (int j = 0; j < 8; j++){
                xf0[j] = xn[(size_t)(quad*8 + j) << 16];
                xf1[j] = xn[(size_t)(quad*8 + j + 32) << 16];
            }
        }

        // prior terms for this lane's 4 px
        float4 puv4 = *(const float4*)(pu + (b<<16) + pxw + (quad<<2));
        float lpu[4], apu[4];
        #pragma unroll
        for (int r = 0; r < 4; r++){
            float pv = ((const float*)&puv4)[r];
            lpu[r] = lamv * pv;
            apu[r] = fmaf(alpv, pv, 1.f);
        }

        #pragma unroll 2
        for (int ct = 0; ct < 8; ct++){
            int rI = (ct << 4) + col;              // I-group row
            int xr = (rI & 7) << 4;                // XOR term (same for I/D/B rows)
            half8 wI0 = *(const half8*)(wsb + ((( rI       << 7) +      qb) ^ xr));
            half8 wI1 = *(const half8*)(wsb + ((( rI       << 7) + 64 + qb) ^ xr));
            half8 wD0 = *(const half8*)(wsb + ((((rI + 128)<< 7) +      qb) ^ xr));
            half8 wD1 = *(const half8*)(wsb + ((((rI + 128)<< 7) + 64 + qb) ^ xr));
            half8 wB0 = *(const half8*)(wsb + ((((rI + 256)<< 7) +      qb) ^ xr));
            half8 wB1 = *(const half8*)(wsb + ((((rI + 256)<< 7) + 64 + qb) ^ xr));

            floatx4 aI = (floatx4){0.f,0.f,0.f,0.f};
            floatx4 aD = (floatx4){0.f,0.f,0.f,0.f};
            floatx4 aB = (floatx4){0.f,0.f,0.f,0.f};
            aI = __builtin_amdgcn_mfma_f32_16x16x32_f16(aX0, wI0, aI, 0, 0, 0);
            aD = __builtin_amdgcn_mfma_f32_16x16x32_f16(aX0, wD0, aD, 0, 0, 0);
            aB = __builtin_amdgcn_mfma_f32_16x16x32_f16(aX0, wB0, aB, 0, 0, 0);
            aI = __builtin_amdgcn_mfma_f32_16x16x32_f16(aX1, wI1, aI, 0, 0, 0);
            aD = __builtin_amdgcn_mfma_f32_16x16x32_f16(aX1, wD1, aD, 0, 0, 0);
            aB = __builtin_amdgcn_mfma_f32_16x16x32_f16(aX1, wB1, aB, 0, 0, 0);

            // epilogue: lane owns 4 consecutive px of channel ct*16+col
            int c = (ct<<4) + col;                 // channel 0..127
            float4 bv = *(const float4*)(bct + (c<<2));  // (bI, bD, bB, -expA)
            au16 ov;
            #pragma unroll
            for (int r = 0; r < 4; r++){
                float sI = aI[r] + bv.x;
                float sD = aD[r] + bv.y;
                float sB = aB[r] + bv.z;
                float dpre  = sD + lpu[r];
                float delta = fmaxf(dpre, 0.f) + __logf(1.f + __expf(-fabsf(dpre)));
                float ab    = __expf(bv.w * delta);
                float uu    = delta * sB * apu[r] * sI;
                (&ov.a.x)[r] = (_Float16)ab;
                (&ov.u.x)[r] = (_Float16)uu;
            }
            size_t u = (((size_t)((b<<7) + c)) << 14) + (pxw >> 2) + quad;
            AU[u] = ov;
        }
    }
}

// ---------------- K34: fused W+H scan v2 — AU loads, raw barriers, 2-deep prefetch ------------
// One block per (b,c) plane, 512 threads = 8 waves. Raw s_barrier (no vmcnt drain!) keeps the
// 2-group-deep AU prefetch in flight across barriers. Sh stores via LDS bounce -> one h4s
// vector store per wave per group (was 32 scalar store instrs/group).
__global__ __launch_bounds__(512) void k_scan_wh(const au16* __restrict__ AU, _Float16* __restrict__ Sh){
    __shared__ float As[8][256], Us[8][256], Wsc[8][256];   // 24 KB
    __shared__ _Float16 Shs[8][256];                        // 4 KB

    const int t    = threadIdx.x;
    const int lane = t & 63;
    const int wave = t >> 6;                       // 0..7 = row within group
    const size_t plane = (size_t)blockIdx.x;       // b*128 + c

    float Hcol = 0.f;                              // column state, thread t owns column t (t<256)

    const size_t ub = (plane << 14) + (wave << 6) + lane;   // au16 units

    au16 cA = AU[ub];                              // group 0, row wave
    au16 cB = AU[ub + 512];                        // group 1 (+8 rows x 64 units)

    auto proc = [&](au16 cur, int gg){
        float ax=(float)cur.a.x, ay=(float)cur.a.y, az=(float)cur.a.z, aw=(float)cur.a.w;
        float ux=(float)cur.u.x, uy=(float)cur.u.y, uz=(float)cur.u.z, uw=(float)cur.u.w;

        // ---- wave W-scan (identical math to K3) ----
        float A = ax, U = ux;
        U = fmaf(ay, U, uy); A *= ay;
        U = fmaf(az, U, uz); A *= az;
        U = fmaf(aw, U, uw); A *= aw;
        #pragma unroll
        for (int off=1; off<64; off<<=1){
            float Apv = __shfl_up(A, off, 64);
            float Upv = __shfl_up(U, off, 64);
            if (lane >= off){ U = fmaf(A, Upv, U); A *= Apv; }
        }
        float h = __shfl_up(U, 1, 64);             // exclusive prefix
        if (lane == 0) h = 0.f;
        float4 o;
        h = fmaf(ax, h, ux); o.x = h;
        h = fmaf(ay, h, uy); o.y = h;
        h = fmaf(az, h, uz); o.z = h;
        h = fmaf(aw, h, uw); o.w = h;

        // ---- park row data in LDS ----
        int c0 = lane << 2;
        *(float4*)&As [wave][c0] = (float4){ax,ay,az,aw};
        *(float4*)&Us [wave][c0] = (float4){ux,uy,uz,uw};
        *(float4*)&Wsc[wave][c0] = o;

        asm volatile("s_waitcnt lgkmcnt(0)" ::: "memory");
        __builtin_amdgcn_sched_barrier(0);
        __builtin_amdgcn_s_barrier();              // raw: vmcnt (AU prefetch) stays in flight
        __builtin_amdgcn_sched_barrier(0);

        // ---- column phase: serial H-recurrence over the 8 rows (identical math to K4) ----
        if (t < 256){
            #pragma unroll
            for (int v = 0; v < 8; v++){
                Hcol = fmaf(As[v][t], Hcol, Us[v][t]);
                Shs[v][t] = (_Float16)(Hcol + Wsc[v][t]);
            }
        }

        asm volatile("s_waitcnt lgkmcnt(0)" ::: "memory");
        __builtin_amdgcn_sched_barrier(0);
        __builtin_amdgcn_s_barrier();
        __builtin_amdgcn_sched_barrier(0);

        // ---- vector store: wave v writes row gg*8+v (512 B, one h4s per lane) ----
        h4s sv = *(h4s*)&Shs[wave][lane << 2];
        *(h4s*)(Sh + (plane << 16) + ((size_t)((gg << 3) + wave) << 8) + (lane << 2)) = sv;
    };

    #pragma unroll 1
    for (int g = 0; g < 32; g += 2){
        proc(cA, g);
        if (g + 2 < 32) cA = AU[ub + (size_t)(g + 2) * 512];
        proc(cB, g + 1);
        if (g + 3 < 32) cB = AU[ub + (size_t)(g + 3) * 512];
    }
}

// ---------------- K5: MFMA output conv (128->64) + residual — swapped operands v2 -------------
__global__ __launch_bounds__(256, 4) void k_out_mfma(const float* __restrict__ x, const _Float16* __restrict__ Sh,
        const _Float16* __restrict__ Wof, const float* __restrict__ bout, const float* __restrict__ gam_p,
        float* __restrict__ out){
    const int t    = threadIdx.x;
    const int lane = t & 63;
    const int wave = t >> 6;
    const int col  = lane & 15;
    const int quad = lane >> 4;
    const int b    = blockIdx.x >> 8;
    const int p0   = (blockIdx.x & 255) << 8;
    const int wn0  = wave << 6;                // this wave's 64 px

    const _Float16* shb = Sh + ((size_t)b<<23) + p0 + wn0;

    floatx4 acc[4][4];                         // [mt=px-tile][nt=out-ch-tile]
    #pragma unroll
    for (int mt = 0; mt < 4; mt++)
        #pragma unroll
        for (int nt = 0; nt < 4; nt++)
            acc[mt][nt] = (floatx4){0.f,0.f,0.f,0.f};

    #pragma unroll
    for (int kc = 0; kc < 4; kc++){
        half8 af[4];                           // Sh[m = wn0+mt*16+col][k = kc*32+quad*8+j]
        #pragma unroll
        for (int mt = 0; mt < 4; mt++)
            #pragma unroll
            for (int j = 0; j < 8; j++)
                af[mt][j] = shb[((size_t)(kc*32 + quad*8 + j)<<16) + mt*16 + col];
        half8 bf[4];                           // Wof[n = nt*16+col][k]  (16B vector loads)
        #pragma unroll
        for (int nt = 0; nt < 4; nt++)
            bf[nt] = *(const half8*)(Wof + (nt*16 + col)*128 + kc*32 + quad*8);
        #pragma unroll
        for (int mt = 0; mt < 4; mt++)
            #pragma unroll
            for (int nt = 0; nt < 4; nt++)
                acc[mt][nt] = __builtin_amdgcn_mfma_f32_16x16x32_f16(af[mt], bf[nt], acc[mt][nt], 0, 0, 0);
    }

    const float gv = gam_p[0];
    #pragma unroll
    for (int nt = 0; nt < 4; nt++){
        int o = nt*16 + col;                   // out channel 0..63
        float bo = bout[o];
        #pragma unroll
        for (int mt = 0; mt < 4; mt++){
            size_t idx = (((size_t)(b*64 + o))<<16) + p0 + wn0 + mt*16 + (quad<<2);
            float4 xv = *(const float4*)(x + idx);
            float4 ov;
            ov.x = fmaf(gv, acc[mt][nt][0] + bo, xv.x);
            ov.y = fmaf(gv, acc[mt][nt][1] + bo, xv.y);
            ov.z = fmaf(gv, acc[mt][nt][2] + bo, xv.z);
            ov.w = fmaf(gv, acc[mt][nt][3] + bo, xv.w);
            *(float4*)(out + idx) = ov;
        }
    }
}

extern "C" void kernel_launch(void* const* d_in, const int* in_sizes, int n_in,
                              void* d_out, int out_size, void* d_ws, size_t ws_size,
                              hipStream_t stream){
    const float* x       = (const float*)d_in[0];
    const float* prior   = (const float*)d_in[1];
    const float* W_in    = (const float*)d_in[2];
    const float* b_in    = (const float*)d_in[3];
    const float* W_out   = (const float*)d_in[4];
    const float* b_out   = (const float*)d_in[5];
    const float* W_delta = (const float*)d_in[6];
    const float* b_delta = (const float*)d_in[7];
    const float* W_B     = (const float*)d_in[8];
    const float* b_B     = (const float*)d_in[9];
    const float* A_param = (const float*)d_in[10];
    const float* lam     = (const float*)d_in[11];
    const float* alp     = (const float*)d_in[12];
    const float* gam     = (const float*)d_in[13];

    float* out = (float*)d_out;
    float* pu  = out + OUT1;                   // prior_up = output 1

    float* ws        = (float*)d_ws;
    _Float16* Wch    = (_Float16*)ws;          // 24576 f16 -> float-offset [0,12288)
    float* bcv       = ws + 12288;             // 384
    float* negA      = ws + 12672;             // 128
    _Float16* Wof    = (_Float16*)(ws + 12800);// 8192 f16 -> [12800,16896)
    float* bct       = ws + 16896;             // 512 floats (128 x float4)
    au16* AU         = (au16*)(ws + 32768);    // BIG/4 units x 16 B = 134 MB
    _Float16* Sh     = (_Float16*)(AU + BIG/4);// BIG f16 = 67 MB  (total ~201 MB)

    hipLaunchKernelGGL(k_prior,  dim3(1024),  dim3(256), 0, stream, prior, pu);
    hipLaunchKernelGGL(k_comb,   dim3(132),   dim3(256), 0, stream, W_in, b_in, W_delta, b_delta,
                       W_B, b_B, A_param, W_out, Wch, bcv, negA, Wof, bct);
    hipLaunchKernelGGL(k_proj_mfma, dim3(512), dim3(512), 0, stream,
                       x, pu, Wch, bct, lam, alp, AU);
    hipLaunchKernelGGL(k_scan_wh, dim3(512), dim3(512), 0, stream, AU, Sh);
    hipLaunchKernelGGL(k_out_mfma, dim3(1024), dim3(256), 0, stream, x, Sh, Wof, b_out, gam, out);
}